// Round 5
// baseline (448.851 us; speedup 1.0000x reference)
//
#include <hip/hip_runtime.h>
#include <math.h>
#include <stdint.h>

#define BB 64
#define SS 512
#define HH 1024
#define TT 21

// DPP-based partial reduce within row of 16, then cross-row shuffles.
template <int CTRL>
__device__ __forceinline__ float dpp_add(float v) {
  int t = __builtin_amdgcn_update_dpp(0, __float_as_int(v), CTRL, 0xF, 0xF, true);
  return v + __int_as_float(t);
}
__device__ __forceinline__ float wave_sum(float v) {
  v = dpp_add<0x121>(v);  // row_ror:1
  v = dpp_add<0x122>(v);  // row_ror:2
  v = dpp_add<0x124>(v);  // row_ror:4
  v = dpp_add<0x128>(v);  // row_ror:8
  v += __shfl_xor(v, 16);
  v += __shfl_xor(v, 32);
  return v;
}

#define DOT4(A, H, WV)    \
  A = fmaf(H.x, WV.x, A); \
  A = fmaf(H.y, WV.y, A); \
  A = fmaf(H.z, WV.z, A); \
  A = fmaf(H.w, WV.w, A)

// ---------------- Kernel 1: emissions = hs @ W^T + bias ----------------
// (unchanged from round 3 for clean attribution)
__global__ __launch_bounds__(192, 4) void k_emis(const float* __restrict__ hs,
                                                 const float* __restrict__ W,
                                                 const float* __restrict__ bias,
                                                 float* __restrict__ emis) {
  __shared__ float part[192 * 14];  // 10752 B
  const int tid = threadIdx.x;
  const int q = tid & 7;     // K-phase 0..7 (covers k4 = 8*i + q)
  const int tmp = tid >> 3;  // 0..23
  const int tg = tmp % 3;    // t-group (7 tags each)
  const int rp = tmp / 3;    // row-pair 0..7 -> rows 2rp, 2rp+1
  const size_t row0 = (size_t)blockIdx.x * 16 + rp * 2;
  const float4* hp0 = (const float4*)(hs + row0 * HH);
  const float4* hp1 = (const float4*)(hs + (row0 + 1) * HH);
  const float* wb0 = W + (size_t)(tg * 7) * HH + q * 4;

  float a0[7] = {0.f, 0.f, 0.f, 0.f, 0.f, 0.f, 0.f};
  float a1[7] = {0.f, 0.f, 0.f, 0.f, 0.f, 0.f, 0.f};
  float4 h0 = hp0[q], h1 = hp1[q];  // i = 0 prefetched
#pragma unroll 2
  for (int i = 0; i < 32; ++i) {
    const float4 hc0 = h0, hc1 = h1;
    if (i < 31) {
      h0 = hp0[(i + 1) * 8 + q];
      h1 = hp1[(i + 1) * 8 + q];
    }
    const float* wb = wb0 + (size_t)i * 32;
#pragma unroll
    for (int lt = 0; lt < 7; ++lt) {
      const float4 w = *(const float4*)(wb + (size_t)lt * HH);
      DOT4(a0[lt], hc0, w);
      DOT4(a1[lt], hc1, w);
    }
  }
#pragma unroll
  for (int lt = 0; lt < 7; ++lt) {
    part[tid * 14 + lt] = a0[lt];
    part[tid * 14 + 7 + lt] = a1[lt];
  }
  __syncthreads();

  // combine 8 K-phases; 336 contiguous outputs per block -> coalesced
  for (int o = tid; o < 16 * TT; o += 192) {
    const int rr = o / TT;
    const int t = o - rr * TT;
    const int tg2 = t / 7;
    const int lt2 = t - tg2 * 7;
    const float* pp = part + (((rr >> 1) * 3 + tg2) * 8) * 14 + (rr & 1) * 7 + lt2;
    float s = ((pp[0] + pp[14]) + (pp[28] + pp[42])) +
              ((pp[56] + pp[70]) + (pp[84] + pp[98]));
    emis[(size_t)blockIdx.x * (16 * TT) + o] = s + bias[t];
  }
}

// ---------------- Kernel 2: CRF forward scan + Viterbi ----------------
// Round-4 (resubmitted round-5; round-4 bench was an infra failure, not a
// kernel verdict): round-3's 650cy/step was exposed global-load latency
// per chunk (VGPR=68 => compiler didn't pipeline; branchy p-loop blocked
// hoisting). Now: emissions staged ONCE in LDS (42KB), per-chunk register
// refill via 8 ds_read_b32 double-buffered one chunk ahead; masks as SGPR
// ballot bitmasks (per-step mk = SALU shift, co-issued); 63 branch-free
// 8-step chunks + peeled 7-step tail. Arithmetic order verbatim.
#define RLF(V, K) __int_as_float(__builtin_amdgcn_readlane(__float_as_int(V), K))

__global__ __launch_bounds__(64, 1) void k_scan(const float* __restrict__ emis,
                                                const int* __restrict__ mask,
                                                const float* __restrict__ trans,
                                                const float* __restrict__ sv,
                                                const float* __restrict__ ev,
                                                float* __restrict__ logZ,
                                                float* __restrict__ pred) {
  __shared__ float sE[SS * TT];            // 42 KiB
  __shared__ unsigned long long mb[9];     // ballot words (+0 pad)
  __shared__ unsigned char bp[SS][32];     // 16 KiB (viterbi only)
  __shared__ unsigned char sTag[SS];       // 0.5 KiB (viterbi only)
  const int lane = threadIdx.x;
  const int j = lane;
  const bool act = (j < TT);
  const int jj = act ? j : 0;
  const int b = blockIdx.x & 63;

  // ---- stage emissions (coalesced) + mask ballot words ----
  {
    const float4* src = (const float4*)(emis + (size_t)b * SS * TT);
    float4* dst = (float4*)sE;
    for (int i = lane; i < SS * TT / 4; i += 64) dst[i] = src[i];
#pragma unroll
    for (int w = 0; w < 8; ++w) {
      unsigned long long bm = __ballot(mask[b * SS + w * 64 + lane] != 0);
      if (lane == 0) mb[w] = bm;
    }
    if (lane == 0) mb[8] = 0ull;
  }
  __syncthreads();

  if (blockIdx.x < 64) {
    // ---- CRF logsumexp scan (exp domain, v = exp(alpha - C)) ----
    float E[TT];
#pragma unroll
    for (int i = 0; i < TT; ++i) E[i] = __expf(trans[i * TT + jj]);
    float v = act ? __expf(sv[jj] + sE[jj]) : 0.f;
    float C = 0.f;
    float nxtv[8];
#pragma unroll
    for (int k = 0; k < 8; ++k) nxtv[k] = sE[(1 + k) * TT + jj];

#define CRF_STEP(P, SHB)                                                      \
  {                                                                           \
    const int mk = (int)((swin >> ((SHB) + (P))) & 1ull);                     \
    const float ge_t = ge[P];                                                 \
    const float v0 = RLF(v, 0), v1 = RLF(v, 1), v2 = RLF(v, 2);               \
    const float v3 = RLF(v, 3), v4 = RLF(v, 4), v5 = RLF(v, 5);               \
    const float v6 = RLF(v, 6), v7 = RLF(v, 7), v8 = RLF(v, 8);               \
    const float v9 = RLF(v, 9), v10 = RLF(v, 10), v11 = RLF(v, 11);           \
    const float v12 = RLF(v, 12), v13 = RLF(v, 13), v14 = RLF(v, 14);         \
    const float v15 = RLF(v, 15), v16 = RLF(v, 16), v17 = RLF(v, 17);         \
    const float v18 = RLF(v, 18), v19 = RLF(v, 19), v20 = RLF(v, 20);         \
    float scale = 1.0f;                                                       \
    if ((P) == 7) {                                                           \
      float m = fmaxf(fmaxf(fmaxf(v0, v1), fmaxf(v2, v3)),                    \
                      fmaxf(fmaxf(v4, v5), fmaxf(v6, v7)));                   \
      m = fmaxf(m, fmaxf(fmaxf(v8, v9), fmaxf(v10, v11)));                    \
      m = fmaxf(m, fmaxf(fmaxf(v12, v13), fmaxf(v14, v15)));                  \
      m = fmaxf(m, fmaxf(fmaxf(v16, v17), fmaxf(v18, v19)));                  \
      m = fmaxf(m, v20);                                                      \
      int ex = (int)((__float_as_uint(m) >> 23) & 255u) - 127;                \
      scale = __uint_as_float((unsigned)(127 - ex) << 23);                    \
      C += (float)ex * 0.6931471805599453f;                                   \
      v *= scale;                                                             \
    }                                                                         \
    float q0 = v0 * E[0], q1 = v1 * E[1], q2 = v2 * E[2];                     \
    q0 = fmaf(v3, E[3], q0);   q1 = fmaf(v4, E[4], q1);   q2 = fmaf(v5, E[5], q2);   \
    q0 = fmaf(v6, E[6], q0);   q1 = fmaf(v7, E[7], q1);   q2 = fmaf(v8, E[8], q2);   \
    q0 = fmaf(v9, E[9], q0);   q1 = fmaf(v10, E[10], q1); q2 = fmaf(v11, E[11], q2); \
    q0 = fmaf(v12, E[12], q0); q1 = fmaf(v13, E[13], q1); q2 = fmaf(v14, E[14], q2); \
    q0 = fmaf(v15, E[15], q0); q1 = fmaf(v16, E[16], q1); q2 = fmaf(v17, E[17], q2); \
    q0 = fmaf(v18, E[18], q0); q1 = fmaf(v19, E[19], q1); q2 = fmaf(v20, E[20], q2); \
    float vn = ((q0 + q1 + q2) * scale) * ge_t;                               \
    v = (act && mk) ? vn : v;                                                 \
  }

    for (int w = 0; w < 8; ++w) {
      const unsigned long long wa = mb[w], wb2 = mb[w + 1];
      const unsigned long long winv = (wa >> 1) | (wb2 << 63);
      const unsigned wlo = __builtin_amdgcn_readfirstlane((unsigned)winv);
      const unsigned whi = __builtin_amdgcn_readfirstlane((unsigned)(winv >> 32));
      const unsigned long long swin = ((unsigned long long)whi << 32) | wlo;
      const int nci = (w < 7) ? 8 : 7;
      for (int ci = 0; ci < nci; ++ci) {
        const int t0 = ((w << 3) + ci) * 8 + 1;
        float cur[8], ge[8];
#pragma unroll
        for (int k = 0; k < 8; ++k) cur[k] = nxtv[k];
#pragma unroll
        for (int k = 0; k < 8; ++k) ge[k] = __expf(cur[k]);
#pragma unroll
        for (int k = 0; k < 8; ++k) {
          int tl = t0 + 8 + k;
          tl = (tl < SS) ? tl : (SS - 1);
          nxtv[k] = sE[tl * TT + jj];
        }
        const int shb = ci << 3;
#pragma unroll
        for (int p = 0; p < 8; ++p) { CRF_STEP(p, shb); }
      }
      if (w == 7) {  // tail chunk: t = 505..511 (no renorm steps)
        float cur[8], ge[8];
#pragma unroll
        for (int k = 0; k < 7; ++k) cur[k] = nxtv[k];
#pragma unroll
        for (int k = 0; k < 7; ++k) ge[k] = __expf(cur[k]);
#pragma unroll
        for (int p = 0; p < 7; ++p) { CRF_STEP(p, 56); }
      }
    }
#undef CRF_STEP
    float wv = act ? v * __expf(ev[jj]) : 0.f;
#pragma unroll
    for (int d = 32; d >= 1; d >>= 1) wv += __shfl_xor(wv, d);
    if (lane == 0) logZ[b] = C + __logf(wv);
  } else {
    // ---- Viterbi: same chunked structure, argmax chains ----
    float Tc[TT];
#pragma unroll
    for (int i = 0; i < TT; ++i) Tc[i] = trans[i * TT + jj];
    float sc = act ? (sv[jj] + sE[jj]) : -3.0e38f;
    float nxtv[8];
#pragma unroll
    for (int k = 0; k < 8; ++k) nxtv[k] = sE[(1 + k) * TT + jj];

#define ARGSTEP(BV, BI, VAL, IDX)          \
  {                                        \
    float x_ = (VAL) + Tc[IDX];            \
    if (x_ > BV) { BV = x_; BI = (IDX); }  \
  }
#define VIT_STEP(P, SHB, TCUR)                                                \
  {                                                                           \
    const int mk = (int)((swin >> ((SHB) + (P))) & 1ull);                     \
    const float e = cur[P];                                                   \
    const float s0 = RLF(sc, 0), s1 = RLF(sc, 1), s2 = RLF(sc, 2);            \
    const float s3 = RLF(sc, 3), s4 = RLF(sc, 4), s5 = RLF(sc, 5);            \
    const float s6 = RLF(sc, 6), s7 = RLF(sc, 7), s8 = RLF(sc, 8);            \
    const float s9 = RLF(sc, 9), s10 = RLF(sc, 10), s11 = RLF(sc, 11);        \
    const float s12 = RLF(sc, 12), s13 = RLF(sc, 13), s14 = RLF(sc, 14);      \
    const float s15 = RLF(sc, 15), s16 = RLF(sc, 16), s17 = RLF(sc, 17);      \
    const float s18 = RLF(sc, 18), s19 = RLF(sc, 19), s20 = RLF(sc, 20);      \
    float b0v, b1v, b2v;                                                      \
    int i0, i1, i2;                                                           \
    b0v = s0 + Tc[0]; i0 = 0;                                                 \
    b1v = s1 + Tc[1]; i1 = 1;                                                 \
    b2v = s2 + Tc[2]; i2 = 2;                                                 \
    ARGSTEP(b0v, i0, s3, 3);   ARGSTEP(b1v, i1, s4, 4);   ARGSTEP(b2v, i2, s5, 5);    \
    ARGSTEP(b0v, i0, s6, 6);   ARGSTEP(b1v, i1, s7, 7);   ARGSTEP(b2v, i2, s8, 8);    \
    ARGSTEP(b0v, i0, s9, 9);   ARGSTEP(b1v, i1, s10, 10); ARGSTEP(b2v, i2, s11, 11);  \
    ARGSTEP(b0v, i0, s12, 12); ARGSTEP(b1v, i1, s13, 13); ARGSTEP(b2v, i2, s14, 14);  \
    ARGSTEP(b0v, i0, s15, 15); ARGSTEP(b1v, i1, s16, 16); ARGSTEP(b2v, i2, s17, 17);  \
    ARGSTEP(b0v, i0, s18, 18); ARGSTEP(b1v, i1, s19, 19); ARGSTEP(b2v, i2, s20, 20);  \
    float best = b0v;                                                         \
    int bi = i0;                                                              \
    if (b1v > best || (b1v == best && i1 < bi)) { best = b1v; bi = i1; }      \
    if (b2v > best || (b2v == best && i2 < bi)) { best = b2v; bi = i2; }      \
    float ns = best + e;                                                      \
    sc = (act && mk) ? ns : sc;                                               \
    if (act) bp[TCUR][j] = (unsigned char)(mk ? bi : j);                      \
  }

    for (int w = 0; w < 8; ++w) {
      const unsigned long long wa = mb[w], wb2 = mb[w + 1];
      const unsigned long long winv = (wa >> 1) | (wb2 << 63);
      const unsigned wlo = __builtin_amdgcn_readfirstlane((unsigned)winv);
      const unsigned whi = __builtin_amdgcn_readfirstlane((unsigned)(winv >> 32));
      const unsigned long long swin = ((unsigned long long)whi << 32) | wlo;
      const int nci = (w < 7) ? 8 : 7;
      for (int ci = 0; ci < nci; ++ci) {
        const int t0 = ((w << 3) + ci) * 8 + 1;
        float cur[8];
#pragma unroll
        for (int k = 0; k < 8; ++k) cur[k] = nxtv[k];
#pragma unroll
        for (int k = 0; k < 8; ++k) {
          int tl = t0 + 8 + k;
          tl = (tl < SS) ? tl : (SS - 1);
          nxtv[k] = sE[tl * TT + jj];
        }
        const int shb = ci << 3;
#pragma unroll
        for (int p = 0; p < 8; ++p) { VIT_STEP(p, shb, t0 + p); }
      }
      if (w == 7) {  // tail chunk: t = 505..511
        float cur[8];
#pragma unroll
        for (int k = 0; k < 7; ++k) cur[k] = nxtv[k];
#pragma unroll
        for (int p = 0; p < 7; ++p) { VIT_STEP(p, 56, 505 + p); }
      }
    }
#undef VIT_STEP
#undef ARGSTEP
    float fsv = act ? (sc + ev[jj]) : -3.0e38f;
    int idx = j;
#pragma unroll
    for (int d = 32; d >= 1; d >>= 1) {
      float ov = __shfl_xor(fsv, d);
      int oi = __shfl_xor(idx, d);
      bool take = (ov > fsv) || (ov == fsv && oi < idx);
      fsv = take ? ov : fsv;
      idx = take ? oi : idx;
    }
    __syncthreads();
    if (lane == 0) {
      int tag = idx;
      sTag[SS - 1] = (unsigned char)tag;
      for (int t = SS - 1; t >= 1; --t) {
        tag = bp[t][tag];
        sTag[t - 1] = (unsigned char)tag;
      }
    }
    __syncthreads();
    // coalesced copy-out: pred = where(mask, tags, 0) as float
    for (int i = lane; i < SS; i += 64) {
      pred[(size_t)b * SS + i] = (float)(mask[b * SS + i] ? (int)sTag[i] : 0);
    }
  }
}

// ---------------- Kernel 3: numerator + loss, one block per batch ----------------
__global__ __launch_bounds__(64, 1) void k_loss(const float* __restrict__ emis,
                                                const int* __restrict__ mask,
                                                const int* __restrict__ labels,
                                                const float* __restrict__ trans,
                                                const float* __restrict__ sv,
                                                const float* __restrict__ ev,
                                                const float* __restrict__ logZ,
                                                float* __restrict__ outv) {
  const int b = blockIdx.x;
  const int lane = threadIdx.x;
  float p = 0.f;
  int cnt = 0;
  for (int t = lane; t < SS; t += 64) {
    cnt += mask[b * SS + t] ? 1 : 0;
    if (t >= 1) {
      const int lp = labels[b * SS + t - 1];
      const int lc = labels[b * SS + t];
      const float mk = (float)mask[b * SS + t];
      p += mk * (trans[lp * TT + lc] + emis[((size_t)b * SS + t) * TT + lc]);
    }
  }
  p = wave_sum(p);
#pragma unroll
  for (int d = 32; d >= 1; d >>= 1) cnt += __shfl_xor(cnt, d);
  if (lane == 0) {
    const int l0 = labels[b * SS];
    float numer = p + sv[l0] + emis[(size_t)b * SS * TT + l0];
    numer += ev[labels[b * SS + cnt - 1]];
    atomicAdd(outv, logZ[b] - numer);  // loss = sum_b (logZ - numerator)
  }
}

extern "C" void kernel_launch(void* const* d_in, const int* in_sizes, int n_in,
                              void* d_out, int out_size, void* d_ws, size_t ws_size,
                              hipStream_t stream) {
  const float* hs = (const float*)d_in[0];
  const int* msk = (const int*)d_in[1];
  const int* lab = (const int*)d_in[2];
  const float* W = (const float*)d_in[3];
  const float* bias = (const float*)d_in[4];
  const float* trans = (const float*)d_in[5];
  const float* sv = (const float*)d_in[6];
  const float* ev = (const float*)d_in[7];
  float* out = (float*)d_out;

  float* emis = (float*)d_ws;                 // 64*512*21 floats
  float* logZ = emis + (size_t)BB * SS * TT;  // 64 floats

  hipMemsetAsync(d_out, 0, 4, stream);  // zero the loss accumulator
  k_emis<<<2048, 192, 0, stream>>>(hs, W, bias, emis);
  k_scan<<<128, 64, 0, stream>>>(emis, msk, trans, sv, ev, logZ, out + 1);
  k_loss<<<64, 64, 0, stream>>>(emis, msk, lab, trans, sv, ev, logZ, out);
}